// Round 18
// baseline (7615.566 us; speedup 1.0000x reference)
//
#include <hip/hip_runtime.h>

#define T_LEN 4096
#define EMB   300
#define HD    256
#define G4    1024      // 4*HD (gate rows per direction)
#define N2    2048      // both directions
#define TAGS  12
#define NEGV  -10000.0f
#define SENT  0x7F7F7F7Fu   // memset byte 0x7F -> 3.396e38f; real values never reach it
#define NLSTM 8             // lstm workers dense at blk 0..7 (4 per direction)
#define NGEMM 2048
#define FEATS0 (NLSTM + NGEMM)
#define NFEATS 64
#define VCH   512           // viterbi feats chunk (24 KB LDS)

// ---------------------------------------------------------------------------
// Fused kernel:
//   blocks 0..7        = persistent BiLSTM (r14 structure: 4 blocks x 1024
//                        thr per direction, quarter gate-rows = 64 w/thread,
//                        one-hop h sentinel exchange — the 5.72 ms config)
//   blocks 8..2055     = gin GEMM (concurrent, middle-out tile order)
//   blocks 2056..2119  = feats consumers: poll Hh sentinels (s_sleep-throttled
//                        spin), compute feats[t][tag]; read-only => no deadlock
// ---------------------------------------------------------------------------
#define MV(K) { const float4 hv = h4[K];                    \
    a0 = fmaf(wA##K.x, hv.x, a0);                           \
    a1 = fmaf(wA##K.y, hv.y, a1);                           \
    a2 = fmaf(wA##K.z, hv.z, a2);                           \
    a3 = fmaf(wA##K.w, hv.w, a3); }

__global__ __launch_bounds__(1024) void fused_gemm_lstm(
    const int* __restrict__ sent, const float* __restrict__ embed,
    const float* __restrict__ Wihf, const float* __restrict__ Wihb,
    const float* __restrict__ bihf, const float* __restrict__ bhhf,
    const float* __restrict__ bihb, const float* __restrict__ bhhb,
    const float* Whh_f, const float* Whh_b,            // NOT restrict (anti-remat)
    const float* __restrict__ h0, const float* __restrict__ c0,
    const float* __restrict__ Wtag, const float* __restrict__ btag,
    float* gin,                      // [T][2048], 0x7F-filled; gemm writes, lstm polls
    float* Hh,                       // [T][512],  0x7F-filled; h exchange + history
    float* feats)                    // [T][12] output of the feats consumers
{
    __shared__ __align__(16) char smem[145*1024];
    const int blk = blockIdx.x;
    const int tid = threadIdx.x;

    if (blk >= FEATS0) {
        // ================= FEATS consumer path =================
        float* Ws  = (float*)smem;               // [12][512] = 24 KB
        float* btS = (float*)(smem + 24576);     // [12]
        for (int i = tid; i < TAGS*512; i += 1024) Ws[i] = Wtag[i];
        if (tid < TAGS) btS[tid] = btag[tid];
        __syncthreads();
        if (tid < 768) {
            const int tl = tid / TAGS;           // 0..63
            const int tg = tid - tl*TAGS;
            const int t  = (blk - FEATS0)*64 + tl;
            const float* wrow = Ws + tg*512;
            float acc = 0.f;
            for (int k = 0; k < 512; ++k) {
                float v = __hip_atomic_load(&Hh[(long)t*512 + k],
                                            __ATOMIC_RELAXED,
                                            __HIP_MEMORY_SCOPE_AGENT);
                while (__float_as_uint(v) == SENT) {     // throttled spin
                    __builtin_amdgcn_s_sleep(127);
                    v = __hip_atomic_load(&Hh[(long)t*512 + k],
                                          __ATOMIC_RELAXED,
                                          __HIP_MEMORY_SCOPE_AGENT);
                }
                acc = fmaf(v, wrow[k], acc);
            }
            feats[t*TAGS + tg] = acc + btS[tg];
        }
        return;
    }

    if (blk >= NLSTM) {
        // ================= GEMM path =================
        float* AsT  = (float*)smem;              // [32][68]
        float* BsT  = (float*)(smem + 8704);     // [32][68]
        int*   sIdx = (int*)  (smem + 17408);    // [64]
        const int g  = blk - NLSTM;
        const int kk8 = g >> 5;                  // 0..63
        const int bn  = g & 31;
        const int bm  = (kk8 & 1) ? (63 - (kk8 >> 1)) : (kk8 >> 1);  // middle-out

        if (tid < 64) sIdx[tid] = sent[bm*64 + tid];
        __syncthreads();

        const int srow = tid >> 4;               // 0..63
        const int skj  = (tid & 15) << 1;        // 0,2,..,30
        const int m0   = (tid >> 5) << 1;        // 0..62 (row pair)
        const int n0   = (tid & 31) << 1;        // 0..62 (col pair)
        const int rn   = bn * 64;
        float acc00=0.f, acc01=0.f, acc10=0.f, acc11=0.f;

        for (int kc = 0; kc < 10; ++kc) {        // K chunks of 32 (guard 300)
            const int k0 = kc*32 + skj;
            float2 va = make_float2(0.f, 0.f), vb = make_float2(0.f, 0.f);
            if (k0 + 1 < EMB) {                  // EMB even: float2 all-or-nothing
                va = *(const float2*)(embed + (long)sIdx[srow]*EMB + k0);
                const int r = rn + srow;
                const float* bsrc = (r < G4) ? (Wihf + (long)r*EMB)
                                             : (Wihb + (long)(r-G4)*EMB);
                vb = *(const float2*)(bsrc + k0);
            }
            AsT[skj*68 + srow]     = va.x;
            AsT[(skj+1)*68 + srow] = va.y;
            BsT[skj*68 + srow]     = vb.x;
            BsT[(skj+1)*68 + srow] = vb.y;
            __syncthreads();
            #pragma unroll
            for (int kk = 0; kk < 32; ++kk) {
                const float2 a2v = *(const float2*)&AsT[kk*68 + m0];
                const float2 b2v = *(const float2*)&BsT[kk*68 + n0];
                acc00 = fmaf(a2v.x, b2v.x, acc00);
                acc01 = fmaf(a2v.x, b2v.y, acc01);
                acc10 = fmaf(a2v.y, b2v.x, acc10);
                acc11 = fmaf(a2v.y, b2v.y, acc11);
            }
            __syncthreads();
        }

        const int c0i = rn + n0, c1i = c0i + 1;
        const float bias0 = (c0i < G4) ? (bihf[c0i] + bhhf[c0i])
                                       : (bihb[c0i-G4] + bhhb[c0i-G4]);
        const float bias1 = (c1i < G4) ? (bihf[c1i] + bhhf[c1i])
                                       : (bihb[c1i-G4] + bhhb[c1i-G4]);
        const long t0 = (long)(bm*64 + m0), t1 = t0 + 1;
        __hip_atomic_store(&gin[t0*N2 + c0i], acc00 + bias0,
                           __ATOMIC_RELAXED, __HIP_MEMORY_SCOPE_AGENT);
        __hip_atomic_store(&gin[t0*N2 + c1i], acc01 + bias1,
                           __ATOMIC_RELAXED, __HIP_MEMORY_SCOPE_AGENT);
        __hip_atomic_store(&gin[t1*N2 + c0i], acc10 + bias0,
                           __ATOMIC_RELAXED, __HIP_MEMORY_SCOPE_AGENT);
        __hip_atomic_store(&gin[t1*N2 + c1i], acc11 + bias1,
                           __ATOMIC_RELAXED, __HIP_MEMORY_SCOPE_AGENT);
        return;
    }

    // ===== LSTM path: blocks 0..7, 4 per direction (r14 structure) =========
    const int dir = blk & 1;            // even->dir0, odd->dir1
    const int b   = blk >> 1;           // unit-slice 0..3 (64 units each)
    const int u     = tid & 63;
    const int wvid  = tid >> 6;         // 0..15
    const int gate  = wvid >> 2;        // wave-uniform
    const int q     = wvid & 3;         // wave-uniform quarter
    const int unit0 = b*64;
    const int row   = gate*64 + u;            // block-local row 0..255
    const int grow  = gate*HD + unit0 + u;    // gate row 0..1023

    float* hS  = (float*)smem;            // 256 floats
    float* ps  = (float*)(smem + 1024);   // [3][256]
    float* gvS = (float*)(smem + 4096);   // 256 floats

    // --- 64 weights (quarter gate row) as named SSA float4, loaded ONCE ---
    const float4* W4 = (const float4*)((dir ? Whh_b : Whh_f)
                                       + (long)grow*HD + q*64);
    const float4 wA0  = W4[0],  wA1  = W4[1],  wA2  = W4[2],  wA3  = W4[3];
    const float4 wA4  = W4[4],  wA5  = W4[5],  wA6  = W4[6],  wA7  = W4[7];
    const float4 wA8  = W4[8],  wA9  = W4[9],  wA10 = W4[10], wA11 = W4[11];
    const float4 wA12 = W4[12], wA13 = W4[13], wA14 = W4[14], wA15 = W4[15];

    float cst = 0.f;
    if (tid < 64) cst = c0[dir*HD + unit0 + tid];       // owners: wave 0
    if (tid < HD) hS[tid] = h0[dir*HD + tid];

    float* ginD = gin + dir*G4;
    float gx = 0.f;
    if (q == 0) {                        // cold poll of first gin word
        const long gi0 = (long)(dir ? T_LEN-1 : 0)*N2 + grow;
        do {
            gx = __hip_atomic_load(&ginD[gi0], __ATOMIC_RELAXED,
                                   __HIP_MEMORY_SCOPE_AGENT);
        } while (__float_as_uint(gx) == SENT);
    }

    #pragma unroll 1
    for (int s = 0; s < T_LEN; ++s) {
        const int t = dir ? (T_LEN-1-s) : s;
        float gxn = 0.f;
        long  gidx = 0;
        if (q == 0 && s+1 < T_LEN) {     // issue next gin load EARLY
            gidx = (long)(dir ? t-1 : t+1)*N2 + grow;
            gxn = __hip_atomic_load(&ginD[gidx], __ATOMIC_RELAXED,
                                    __HIP_MEMORY_SCOPE_AGENT);
            __builtin_amdgcn_sched_barrier(0);
        }

        __syncthreads();                         // (A) hS(s) complete
        const float4* h4 = (const float4*)(hS + q*64);   // uniform broadcast
        float a0=0.f, a1=0.f, a2=0.f, a3=0.f;
        MV(0)  MV(1)  MV(2)  MV(3)
        MV(4)  MV(5)  MV(6)  MV(7)
        MV(8)  MV(9)  MV(10) MV(11)
        MV(12) MV(13) MV(14) MV(15)
        const float a = (a0+a1)+(a2+a3);
        if (q != 0) ps[(q-1)*256 + row] = a;
        __syncthreads();                         // (B) partials ready

        if (q == 0) {                            // finalize + activate (256 thr)
            const float raw = a + ps[row] + ps[256+row] + ps[512+row] + gx;
            gvS[row] = (gate == 2) ? tanhf(raw) : 1.f/(1.f + expf(-raw));
        }
        __syncthreads();                         // (C) gvS ready

        if (tid < 64) {                          // wave 0 = owners: c/h + publish
            const float i_ = gvS[tid],       f_ = gvS[64+tid];
            const float g_ = gvS[128+tid],   o_ = gvS[192+tid];
            cst = fmaf(f_, cst, i_*g_);
            const float hv = o_ * tanhf(cst);
            hS[unit0 + tid] = hv;                // own slice: LDS only
            __hip_atomic_store(&Hh[(long)t*512 + dir*HD + unit0 + tid], hv,
                               __ATOMIC_RELAXED, __HIP_MEMORY_SCOPE_AGENT);
        } else if (tid < 256 && s+1 < T_LEN) {   // waves 1-3: 192 pollers
            const int fid = tid - 64;
            const int gu  = (fid < unit0) ? fid : fid + 64;
            const long idx = (long)t*512 + dir*HD + gu;
            float v;
            do {
                v = __hip_atomic_load(&Hh[idx], __ATOMIC_RELAXED,
                                      __HIP_MEMORY_SCOPE_AGENT);
            } while (__float_as_uint(v) == SENT);
            hS[gu] = v;
        }

        if (q == 0 && s+1 < T_LEN) {             // check-late gin
            while (__float_as_uint(gxn) == SENT)
                gxn = __hip_atomic_load(&ginD[gidx], __ATOMIC_RELAXED,
                                        __HIP_MEMORY_SCOPE_AGENT);
        }
        gx = gxn;
    }
}

// ---------------------------------------------------------------------------
// Kernel 4: Viterbi — 3-phase, single wave of 64 lanes (r17 structure).
// ---------------------------------------------------------------------------
__global__ __launch_bounds__(64) void viterbi_kernel(
    const float* __restrict__ feats, const float* __restrict__ trans,
    float* __restrict__ fvstore, float* __restrict__ out)
{
    __shared__ __align__(16) float fS[VCH*TAGS];        // 24 KB feats chunk
    __shared__ __align__(16) float fvS[16];
    __shared__ __align__(16) float trS[TAGS*TAGS];
    __shared__ unsigned char bps[T_LEN*TAGS];           // 48 KB backpointers
    const int lane = threadIdx.x;

    for (int i = lane; i < TAGS*TAGS; i += 64) trS[i] = trans[i];

    const int trow = (lane < TAGS) ? lane : 0;
    float tr[TAGS];
    #pragma unroll
    for (int f = 0; f < TAGS; ++f) tr[f] = trans[trow*TAGS + f];

    float fvv[TAGS];
    #pragma unroll
    for (int f = 0; f < TAGS; ++f) fvv[f] = (f == 10) ? 0.f : NEGV;  // START=10

    // ---------------- Phase 1: forward max-scan ----------------
    for (int c = 0; c < T_LEN/VCH; ++c) {
        __syncthreads();
        {
            const float4* src = (const float4*)(feats + (long)c*VCH*TAGS);
            float4* dst = (float4*)fS;
            #pragma unroll 4
            for (int i = lane; i < VCH*TAGS/4; i += 64) dst[i] = src[i];
        }
        __syncthreads();
        for (int s = 0; s < VCH; ++s) {
            const int t = c*VCH + s;
            if (lane < TAGS) {
                fvstore[(long)t*TAGS + lane] = fvv[lane];   // fv_pre
                float cand[TAGS];
                #pragma unroll
                for (int f = 0; f < TAGS; ++f) cand[f] = fvv[f] + tr[f];
                const float m =
                    fmaxf(fmaxf(fmaxf(fmaxf(cand[0],cand[1]), fmaxf(cand[2],cand[3])),
                                fmaxf(fmaxf(cand[4],cand[5]), fmaxf(cand[6],cand[7]))),
                          fmaxf(fmaxf(cand[8],cand[9]), fmaxf(cand[10],cand[11])));
                fvS[lane] = m + fS[s*TAGS + lane];
            }
            __syncthreads();
            const float4 A = *(const float4*)&fvS[0];
            const float4 B = *(const float4*)&fvS[4];
            const float4 C = *(const float4*)&fvS[8];
            fvv[0]=A.x; fvv[1]=A.y; fvv[2]=A.z; fvv[3]=A.w;
            fvv[4]=B.x; fvv[5]=B.y; fvv[6]=B.z; fvv[7]=B.w;
            fvv[8]=C.x; fvv[9]=C.y; fvv[10]=C.z; fvv[11]=C.w;
            __syncthreads();
        }
    }

    // ---------------- Phase 2: parallel backpointer recovery ----------------
    __syncthreads();
    for (int t = lane; t < T_LEN; t += 64) {
        const float4 F0 = *(const float4*)(fvstore + (long)t*TAGS);
        const float4 F1 = *(const float4*)(fvstore + (long)t*TAGS + 4);
        const float4 F2 = *(const float4*)(fvstore + (long)t*TAGS + 8);
        const float fp[TAGS] = {F0.x,F0.y,F0.z,F0.w,
                                F1.x,F1.y,F1.z,F1.w,
                                F2.x,F2.y,F2.z,F2.w};
        #pragma unroll
        for (int to = 0; to < TAGS; ++to) {
            float best = -3.4e38f; int bp = 0;
            #pragma unroll
            for (int f = 0; f < TAGS; ++f) {
                const float v = fp[f] + trS[to*TAGS + f];
                if (v > best) { best = v; bp = f; }   // strict > = np first-max
            }
            bps[t*TAGS + to] = (unsigned char)bp;
        }
    }
    __syncthreads();

    // ---------------- Phase 3: terminal + serial backtrack ----------------
    if (lane == 0) {
        float bestv = -3.4e38f; int best = 0;
        #pragma unroll
        for (int g = 0; g < TAGS; ++g) {
            const float v = fvv[g] + trS[11*TAGS + g];    // STOP = 11
            if (v > bestv) { bestv = v; best = g; }
        }
        out[0] = bestv;
        int cur = best;
        for (int t = T_LEN-1; t >= 0; --t) {
            out[1+t] = (float)cur;
            cur = bps[t*TAGS + cur];
        }
    }
}

// ---------------------------------------------------------------------------
// Host launch.  ws layout (floats):
//   gin     [4096*2048] = 33.5 MB  (0x7F sentinel-filled each launch)
//   Hh      [4096*512]  =  8.4 MB  (0x7F sentinel-filled each launch)
//   feats   [4096*12]   =  0.2 MB
//   fvstore [4096*12]   =  0.2 MB
// ---------------------------------------------------------------------------
extern "C" void kernel_launch(void* const* d_in, const int* in_sizes, int n_in,
                              void* d_out, int out_size, void* d_ws, size_t ws_size,
                              hipStream_t stream)
{
    (void)in_sizes; (void)n_in; (void)out_size; (void)ws_size;
    const int*   sentence = (const int*)  d_in[0];
    const float* h0       = (const float*)d_in[1];
    const float* c0       = (const float*)d_in[2];
    const float* embed    = (const float*)d_in[3];
    const float* Wihf     = (const float*)d_in[4];
    const float* Whhf     = (const float*)d_in[5];
    const float* bihf     = (const float*)d_in[6];
    const float* bhhf     = (const float*)d_in[7];
    const float* Wihb     = (const float*)d_in[8];
    const float* Whhb     = (const float*)d_in[9];
    const float* bihb     = (const float*)d_in[10];
    const float* bhhb     = (const float*)d_in[11];
    const float* Wtag     = (const float*)d_in[12];
    const float* btag     = (const float*)d_in[13];
    const float* trans    = (const float*)d_in[14];
    float* out = (float*)d_out;

    float* gin     = (float*)d_ws;
    float* Hh      = gin   + (long)T_LEN*N2;
    float* feats   = Hh    + (long)T_LEN*512;
    float* fvstore = feats + (long)T_LEN*TAGS;

    hipMemsetAsync(gin, 0x7F, (size_t)T_LEN*N2*sizeof(float), stream);
    hipMemsetAsync(Hh,  0x7F, (size_t)T_LEN*512*sizeof(float), stream);

    fused_gemm_lstm<<<FEATS0 + NFEATS, 1024, 0, stream>>>(
        sentence, embed, Wihf, Wihb, bihf, bhhf, bihb, bhhb,
        Whhf, Whhb, h0, c0, Wtag, btag, gin, Hh, feats);
    viterbi_kernel<<<1, 64, 0, stream>>>(feats, trans, fvstore, out);
}

// Round 19
// 6631.090 us; speedup vs baseline: 1.1485x; 1.1485x over previous
//
#include <hip/hip_runtime.h>

#define T_LEN 4096
#define EMB   300
#define HD    256
#define G4    1024      // 4*HD (gate rows per direction)
#define N2    2048      // both directions
#define TAGS  12
#define NEGV  -10000.0f
#define SENT  0x7F7F7F7Fu   // memset byte 0x7F -> 3.396e38f; real values never reach it
#define NLSTM 29            // lstm sub-grid (8 workers at blk%8 in {0,4} + spacers)
#define VCH   512           // viterbi feats chunk (24 KB LDS)

// ---------------------------------------------------------------------------
// Fused kernel (r14's exact 5.72 ms configuration):
//   blocks 0..28  = persistent BiLSTM (4 blocks x 1024 thr per direction,
//                   quarter gate-rows = 64 w/thread, one-hop h sentinel
//                   exchange, workers at blk%8 in {0,4})
//   blocks 29..   = gin GEMM (concurrent, middle-out tile order)
// ---------------------------------------------------------------------------
#define MV(K) { const float4 hv = h4[K];                    \
    a0 = fmaf(wA##K.x, hv.x, a0);                           \
    a1 = fmaf(wA##K.y, hv.y, a1);                           \
    a2 = fmaf(wA##K.z, hv.z, a2);                           \
    a3 = fmaf(wA##K.w, hv.w, a3); }

__global__ __launch_bounds__(1024) void fused_gemm_lstm(
    const int* __restrict__ sent, const float* __restrict__ embed,
    const float* __restrict__ Wihf, const float* __restrict__ Wihb,
    const float* __restrict__ bihf, const float* __restrict__ bhhf,
    const float* __restrict__ bihb, const float* __restrict__ bhhb,
    const float* Whh_f, const float* Whh_b,            // NOT restrict (anti-remat)
    const float* __restrict__ h0, const float* __restrict__ c0,
    float* gin,                      // [T][2048], 0x7F-filled; gemm writes, lstm polls
    float* Hh)                       // [T][512],  0x7F-filled; h exchange + history
{
    __shared__ __align__(16) char smem[145*1024];
    const int blk = blockIdx.x;
    const int tid = threadIdx.x;

    if (blk >= NLSTM) {
        // ================= GEMM path =================
        float* AsT  = (float*)smem;              // [32][68]
        float* BsT  = (float*)(smem + 8704);     // [32][68]
        int*   sIdx = (int*)  (smem + 17408);    // [64]
        const int g  = blk - NLSTM;
        const int kk8 = g >> 5;                  // 0..63
        const int bn  = g & 31;
        const int bm  = (kk8 & 1) ? (63 - (kk8 >> 1)) : (kk8 >> 1);  // middle-out

        if (tid < 64) sIdx[tid] = sent[bm*64 + tid];
        __syncthreads();

        const int srow = tid >> 4;               // 0..63
        const int skj  = (tid & 15) << 1;        // 0,2,..,30
        const int m0   = (tid >> 5) << 1;        // 0..62 (row pair)
        const int n0   = (tid & 31) << 1;        // 0..62 (col pair)
        const int rn   = bn * 64;
        float acc00=0.f, acc01=0.f, acc10=0.f, acc11=0.f;

        for (int kc = 0; kc < 10; ++kc) {        // K chunks of 32 (guard 300)
            const int k0 = kc*32 + skj;
            float2 va = make_float2(0.f, 0.f), vb = make_float2(0.f, 0.f);
            if (k0 + 1 < EMB) {                  // EMB even: float2 all-or-nothing
                va = *(const float2*)(embed + (long)sIdx[srow]*EMB + k0);
                const int r = rn + srow;
                const float* bsrc = (r < G4) ? (Wihf + (long)r*EMB)
                                             : (Wihb + (long)(r-G4)*EMB);
                vb = *(const float2*)(bsrc + k0);
            }
            AsT[skj*68 + srow]     = va.x;
            AsT[(skj+1)*68 + srow] = va.y;
            BsT[skj*68 + srow]     = vb.x;
            BsT[(skj+1)*68 + srow] = vb.y;
            __syncthreads();
            #pragma unroll
            for (int kk = 0; kk < 32; ++kk) {
                const float2 a2v = *(const float2*)&AsT[kk*68 + m0];
                const float2 b2v = *(const float2*)&BsT[kk*68 + n0];
                acc00 = fmaf(a2v.x, b2v.x, acc00);
                acc01 = fmaf(a2v.x, b2v.y, acc01);
                acc10 = fmaf(a2v.y, b2v.x, acc10);
                acc11 = fmaf(a2v.y, b2v.y, acc11);
            }
            __syncthreads();
        }

        const int c0i = rn + n0, c1i = c0i + 1;
        const float bias0 = (c0i < G4) ? (bihf[c0i] + bhhf[c0i])
                                       : (bihb[c0i-G4] + bhhb[c0i-G4]);
        const float bias1 = (c1i < G4) ? (bihf[c1i] + bhhf[c1i])
                                       : (bihb[c1i-G4] + bhhb[c1i-G4]);
        const long t0 = (long)(bm*64 + m0), t1 = t0 + 1;
        __hip_atomic_store(&gin[t0*N2 + c0i], acc00 + bias0,
                           __ATOMIC_RELAXED, __HIP_MEMORY_SCOPE_AGENT);
        __hip_atomic_store(&gin[t0*N2 + c1i], acc01 + bias1,
                           __ATOMIC_RELAXED, __HIP_MEMORY_SCOPE_AGENT);
        __hip_atomic_store(&gin[t1*N2 + c0i], acc10 + bias0,
                           __ATOMIC_RELAXED, __HIP_MEMORY_SCOPE_AGENT);
        __hip_atomic_store(&gin[t1*N2 + c1i], acc11 + bias1,
                           __ATOMIC_RELAXED, __HIP_MEMORY_SCOPE_AGENT);
        return;
    }

    // ================= LSTM path (r14 structure, verbatim) =================
    const int m8 = blk & 7;
    if (m8 != 0 && m8 != 4) return;     // XCD placement spacers
    const int dir = (m8 == 4);
    const int b   = blk >> 3;           // unit-slice 0..3
    const int u     = tid & 63;
    const int wvid  = tid >> 6;         // 0..15
    const int gate  = wvid >> 2;        // wave-uniform
    const int q     = wvid & 3;         // wave-uniform quarter
    const int unit0 = b*64;
    const int row   = gate*64 + u;            // block-local row 0..255
    const int grow  = gate*HD + unit0 + u;    // gate row 0..1023

    float* hS  = (float*)smem;            // 256 floats
    float* ps  = (float*)(smem + 1024);   // [3][256]
    float* gvS = (float*)(smem + 4096);   // 256 floats

    // --- 64 weights as named SSA float4, loaded ONCE ---
    const float4* W4 = (const float4*)((dir ? Whh_b : Whh_f)
                                       + (long)grow*HD + q*64);
    const float4 wA0  = W4[0],  wA1  = W4[1],  wA2  = W4[2],  wA3  = W4[3];
    const float4 wA4  = W4[4],  wA5  = W4[5],  wA6  = W4[6],  wA7  = W4[7];
    const float4 wA8  = W4[8],  wA9  = W4[9],  wA10 = W4[10], wA11 = W4[11];
    const float4 wA12 = W4[12], wA13 = W4[13], wA14 = W4[14], wA15 = W4[15];

    float cst = 0.f;
    if (tid < 64) cst = c0[dir*HD + unit0 + tid];       // owners: wave 0
    if (tid < HD) hS[tid] = h0[dir*HD + tid];

    float* ginD = gin + dir*G4;
    float gx;
    {   // initial gin word: cold poll
        const long gi0 = (long)(dir ? T_LEN-1 : 0)*N2 + grow;
        do {
            gx = __hip_atomic_load(&ginD[gi0], __ATOMIC_RELAXED,
                                   __HIP_MEMORY_SCOPE_AGENT);
        } while (__float_as_uint(gx) == SENT);
    }

    #pragma unroll 1
    for (int s = 0; s < T_LEN; ++s) {
        const int t = dir ? (T_LEN-1-s) : s;
        float gxn = 0.f;
        long  gidx = 0;
        if (s+1 < T_LEN) {                     // issue next-step gin load EARLY
            gidx = (long)(dir ? t-1 : t+1)*N2 + grow;
            gxn = __hip_atomic_load(&ginD[gidx], __ATOMIC_RELAXED,
                                    __HIP_MEMORY_SCOPE_AGENT);
            __builtin_amdgcn_sched_barrier(0); // pin the early issue
        }

        __syncthreads();                       // (A) hS(s) complete
        const float4* h4 = (const float4*)(hS + q*64);   // uniform-addr broadcast
        float a0=0.f, a1=0.f, a2=0.f, a3=0.f;
        MV(0)  MV(1)  MV(2)  MV(3)
        MV(4)  MV(5)  MV(6)  MV(7)
        MV(8)  MV(9)  MV(10) MV(11)
        MV(12) MV(13) MV(14) MV(15)
        const float a = (a0+a1)+(a2+a3);
        if (q != 0) ps[(q-1)*256 + row] = a;
        __syncthreads();                       // (B) partials ready

        if (q == 0) {                          // waves 0,4,8,12: finalize + activate
            const float raw = a + ps[row] + ps[256+row] + ps[512+row] + gx;
            gvS[row] = (gate == 2) ? tanhf(raw) : 1.f/(1.f + expf(-raw));
        }
        __syncthreads();                       // (C) gvS ready

        if (tid < 64) {                        // wave 0 = owners: c/h update + publish
            const float i_ = gvS[tid],       f_ = gvS[64+tid];
            const float g_ = gvS[128+tid],   o_ = gvS[192+tid];
            cst = fmaf(f_, cst, i_*g_);
            const float hv = o_ * tanhf(cst);
            hS[unit0 + tid] = hv;              // own slice: LDS only
            __hip_atomic_store(&Hh[(long)t*512 + dir*HD + unit0 + tid], hv,
                               __ATOMIC_RELAXED, __HIP_MEMORY_SCOPE_AGENT);
        } else if (tid < 256 && s+1 < T_LEN) { // waves 1-3: poll one foreign word each
            const int fidx = tid - 64;                      // 0..191
            const int gu   = (fidx < unit0) ? fidx : fidx + 64;
            const long idx = (long)t*512 + dir*HD + gu;
            float v;
            do {
                v = __hip_atomic_load(&Hh[idx], __ATOMIC_RELAXED,
                                      __HIP_MEMORY_SCOPE_AGENT);
            } while (__float_as_uint(v) == SENT);
            hS[gu] = v;
        }

        if (s+1 < T_LEN) {                     // check-late: usually already ready
            while (__float_as_uint(gxn) == SENT)
                gxn = __hip_atomic_load(&ginD[gidx], __ATOMIC_RELAXED,
                                        __HIP_MEMORY_SCOPE_AGENT);
        }
        gx = gxn;
    }
}

// ---------------------------------------------------------------------------
// Kernel 3: feats[t][tag] = [hf|hb][t] . W_tag[tag] + b_tag  (separate kernel
// — r18 proved polling-consumer fusion slows the LSTM's coherence path)
// ---------------------------------------------------------------------------
__global__ __launch_bounds__(192) void feats_kernel(
    const float* __restrict__ Hhist, const float* __restrict__ Wtag,
    const float* __restrict__ btag, float* __restrict__ feats)
{
    __shared__ __align__(16) float Ws[TAGS][512];
    const int tid = threadIdx.x;
    for (int i = tid; i < TAGS*512; i += 192) Ws[0][i] = Wtag[i];
    __syncthreads();
    const int tl = tid / TAGS;            // 0..15
    const int tg = tid % TAGS;
    const int t  = blockIdx.x * 16 + tl;
    const float4* hrow = (const float4*)(Hhist + (long)t*512);
    const float4* wrow = (const float4*)(&Ws[tg][0]);
    float a0=0.f,a1=0.f,a2=0.f,a3=0.f;
    #pragma unroll 8
    for (int k = 0; k < 128; ++k) {
        const float4 h = hrow[k];
        const float4 ww = wrow[k];
        a0=fmaf(h.x,ww.x,a0); a1=fmaf(h.y,ww.y,a1);
        a2=fmaf(h.z,ww.z,a2); a3=fmaf(h.w,ww.w,a3);
    }
    feats[t*TAGS + tg] = ((a0+a1)+(a2+a3)) + btag[tg];
}

// ---------------------------------------------------------------------------
// Kernel 4: Viterbi — 3-phase, single wave of 64 lanes (r17 structure:
// register-batched phase 2).
// ---------------------------------------------------------------------------
__global__ __launch_bounds__(64) void viterbi_kernel(
    const float* __restrict__ feats, const float* __restrict__ trans,
    float* __restrict__ fvstore, float* __restrict__ out)
{
    __shared__ __align__(16) float fS[VCH*TAGS];        // 24 KB feats chunk
    __shared__ __align__(16) float fvS[16];
    __shared__ __align__(16) float trS[TAGS*TAGS];
    __shared__ unsigned char bps[T_LEN*TAGS];           // 48 KB backpointers
    const int lane = threadIdx.x;

    for (int i = lane; i < TAGS*TAGS; i += 64) trS[i] = trans[i];

    const int trow = (lane < TAGS) ? lane : 0;
    float tr[TAGS];
    #pragma unroll
    for (int f = 0; f < TAGS; ++f) tr[f] = trans[trow*TAGS + f];

    float fvv[TAGS];
    #pragma unroll
    for (int f = 0; f < TAGS; ++f) fvv[f] = (f == 10) ? 0.f : NEGV;  // START=10

    // ---------------- Phase 1: forward max-scan ----------------
    for (int c = 0; c < T_LEN/VCH; ++c) {
        __syncthreads();
        {
            const float4* src = (const float4*)(feats + (long)c*VCH*TAGS);
            float4* dst = (float4*)fS;
            #pragma unroll 4
            for (int i = lane; i < VCH*TAGS/4; i += 64) dst[i] = src[i];
        }
        __syncthreads();
        for (int s = 0; s < VCH; ++s) {
            const int t = c*VCH + s;
            if (lane < TAGS) {
                fvstore[(long)t*TAGS + lane] = fvv[lane];   // fv_pre
                float cand[TAGS];
                #pragma unroll
                for (int f = 0; f < TAGS; ++f) cand[f] = fvv[f] + tr[f];
                const float m =
                    fmaxf(fmaxf(fmaxf(fmaxf(cand[0],cand[1]), fmaxf(cand[2],cand[3])),
                                fmaxf(fmaxf(cand[4],cand[5]), fmaxf(cand[6],cand[7]))),
                          fmaxf(fmaxf(cand[8],cand[9]), fmaxf(cand[10],cand[11])));
                fvS[lane] = m + fS[s*TAGS + lane];
            }
            __syncthreads();
            const float4 A = *(const float4*)&fvS[0];
            const float4 B = *(const float4*)&fvS[4];
            const float4 C = *(const float4*)&fvS[8];
            fvv[0]=A.x; fvv[1]=A.y; fvv[2]=A.z; fvv[3]=A.w;
            fvv[4]=B.x; fvv[5]=B.y; fvv[6]=B.z; fvv[7]=B.w;
            fvv[8]=C.x; fvv[9]=C.y; fvv[10]=C.z; fvv[11]=C.w;
            __syncthreads();
        }
    }

    // ---------------- Phase 2: parallel backpointer recovery ----------------
    __syncthreads();
    for (int t = lane; t < T_LEN; t += 64) {
        const float4 F0 = *(const float4*)(fvstore + (long)t*TAGS);
        const float4 F1 = *(const float4*)(fvstore + (long)t*TAGS + 4);
        const float4 F2 = *(const float4*)(fvstore + (long)t*TAGS + 8);
        const float fp[TAGS] = {F0.x,F0.y,F0.z,F0.w,
                                F1.x,F1.y,F1.z,F1.w,
                                F2.x,F2.y,F2.z,F2.w};
        #pragma unroll
        for (int to = 0; to < TAGS; ++to) {
            float best = -3.4e38f; int bp = 0;
            #pragma unroll
            for (int f = 0; f < TAGS; ++f) {
                const float v = fp[f] + trS[to*TAGS + f];
                if (v > best) { best = v; bp = f; }   // strict > = np first-max
            }
            bps[t*TAGS + to] = (unsigned char)bp;
        }
    }
    __syncthreads();

    // ---------------- Phase 3: terminal + serial backtrack ----------------
    if (lane == 0) {
        float bestv = -3.4e38f; int best = 0;
        #pragma unroll
        for (int g = 0; g < TAGS; ++g) {
            const float v = fvv[g] + trS[11*TAGS + g];    // STOP = 11
            if (v > bestv) { bestv = v; best = g; }
        }
        out[0] = bestv;
        int cur = best;
        for (int t = T_LEN-1; t >= 0; --t) {
            out[1+t] = (float)cur;
            cur = bps[t*TAGS + cur];
        }
    }
}

// ---------------------------------------------------------------------------
// Host launch.  ws layout (floats):
//   gin     [4096*2048] = 33.5 MB  (0x7F sentinel-filled each launch)
//   Hh      [4096*512]  =  8.4 MB  (0x7F sentinel-filled each launch)
//   feats   [4096*12]   =  0.2 MB
//   fvstore [4096*12]   =  0.2 MB
// ---------------------------------------------------------------------------
extern "C" void kernel_launch(void* const* d_in, const int* in_sizes, int n_in,
                              void* d_out, int out_size, void* d_ws, size_t ws_size,
                              hipStream_t stream)
{
    (void)in_sizes; (void)n_in; (void)out_size; (void)ws_size;
    const int*   sentence = (const int*)  d_in[0];
    const float* h0       = (const float*)d_in[1];
    const float* c0       = (const float*)d_in[2];
    const float* embed    = (const float*)d_in[3];
    const float* Wihf     = (const float*)d_in[4];
    const float* Whhf     = (const float*)d_in[5];
    const float* bihf     = (const float*)d_in[6];
    const float* bhhf     = (const float*)d_in[7];
    const float* Wihb     = (const float*)d_in[8];
    const float* Whhb     = (const float*)d_in[9];
    const float* bihb     = (const float*)d_in[10];
    const float* bhhb     = (const float*)d_in[11];
    const float* Wtag     = (const float*)d_in[12];
    const float* btag     = (const float*)d_in[13];
    const float* trans    = (const float*)d_in[14];
    float* out = (float*)d_out;

    float* gin     = (float*)d_ws;
    float* Hh      = gin   + (long)T_LEN*N2;
    float* feats   = Hh    + (long)T_LEN*512;
    float* fvstore = feats + (long)T_LEN*TAGS;

    hipMemsetAsync(gin, 0x7F, (size_t)T_LEN*N2*sizeof(float), stream);
    hipMemsetAsync(Hh,  0x7F, (size_t)T_LEN*512*sizeof(float), stream);

    fused_gemm_lstm<<<NLSTM + 2048, 1024, 0, stream>>>(
        sentence, embed, Wihf, Wihb, bihf, bhhf, bihb, bhhb,
        Whhf, Whhb, h0, c0, gin, Hh);
    feats_kernel<<<T_LEN/16, 192, 0, stream>>>(Hh, Wtag, btag, feats);
    viterbi_kernel<<<1, 64, 0, stream>>>(feats, trans, fvstore, out);
}

// Round 20
// 6334.333 us; speedup vs baseline: 1.2023x; 1.0468x over previous
//
#include <hip/hip_runtime.h>

#define T_LEN 4096
#define EMB   300
#define HD    256
#define G4    1024      // 4*HD (gate rows per direction)
#define N2    2048      // both directions
#define TAGS  12
#define NEGV  -10000.0f
#define SENT  0x7F7F7F7Fu   // memset byte 0x7F -> 3.396e38f; real values never reach it
#define NLSTM 29            // lstm sub-grid (8 workers at blk%8 in {0,4} + spacers)
#define VCH   512           // viterbi feats chunk (24 KB LDS)

// ---------------------------------------------------------------------------
// Fused kernel (r14/r19's exact 5.72 ms configuration):
//   blocks 0..28  = persistent BiLSTM (4 blocks x 1024 thr per direction,
//                   quarter gate-rows = 64 w/thread, one-hop h sentinel
//                   exchange, workers at blk%8 in {0,4})
//   blocks 29..   = gin GEMM (concurrent, middle-out tile order)
// ---------------------------------------------------------------------------
#define MV(K) { const float4 hv = h4[K];                    \
    a0 = fmaf(wA##K.x, hv.x, a0);                           \
    a1 = fmaf(wA##K.y, hv.y, a1);                           \
    a2 = fmaf(wA##K.z, hv.z, a2);                           \
    a3 = fmaf(wA##K.w, hv.w, a3); }

__global__ __launch_bounds__(1024) void fused_gemm_lstm(
    const int* __restrict__ sent, const float* __restrict__ embed,
    const float* __restrict__ Wihf, const float* __restrict__ Wihb,
    const float* __restrict__ bihf, const float* __restrict__ bhhf,
    const float* __restrict__ bihb, const float* __restrict__ bhhb,
    const float* Whh_f, const float* Whh_b,            // NOT restrict (anti-remat)
    const float* __restrict__ h0, const float* __restrict__ c0,
    float* gin,                      // [T][2048], 0x7F-filled; gemm writes, lstm polls
    float* Hh)                       // [T][512],  0x7F-filled; h exchange + history
{
    __shared__ __align__(16) char smem[145*1024];
    const int blk = blockIdx.x;
    const int tid = threadIdx.x;

    if (blk >= NLSTM) {
        // ================= GEMM path =================
        float* AsT  = (float*)smem;              // [32][68]
        float* BsT  = (float*)(smem + 8704);     // [32][68]
        int*   sIdx = (int*)  (smem + 17408);    // [64]
        const int g  = blk - NLSTM;
        const int kk8 = g >> 5;                  // 0..63
        const int bn  = g & 31;
        const int bm  = (kk8 & 1) ? (63 - (kk8 >> 1)) : (kk8 >> 1);  // middle-out

        if (tid < 64) sIdx[tid] = sent[bm*64 + tid];
        __syncthreads();

        const int srow = tid >> 4;               // 0..63
        const int skj  = (tid & 15) << 1;        // 0,2,..,30
        const int m0   = (tid >> 5) << 1;        // 0..62 (row pair)
        const int n0   = (tid & 31) << 1;        // 0..62 (col pair)
        const int rn   = bn * 64;
        float acc00=0.f, acc01=0.f, acc10=0.f, acc11=0.f;

        for (int kc = 0; kc < 10; ++kc) {        // K chunks of 32 (guard 300)
            const int k0 = kc*32 + skj;
            float2 va = make_float2(0.f, 0.f), vb = make_float2(0.f, 0.f);
            if (k0 + 1 < EMB) {                  // EMB even: float2 all-or-nothing
                va = *(const float2*)(embed + (long)sIdx[srow]*EMB + k0);
                const int r = rn + srow;
                const float* bsrc = (r < G4) ? (Wihf + (long)r*EMB)
                                             : (Wihb + (long)(r-G4)*EMB);
                vb = *(const float2*)(bsrc + k0);
            }
            AsT[skj*68 + srow]     = va.x;
            AsT[(skj+1)*68 + srow] = va.y;
            BsT[skj*68 + srow]     = vb.x;
            BsT[(skj+1)*68 + srow] = vb.y;
            __syncthreads();
            #pragma unroll
            for (int kk = 0; kk < 32; ++kk) {
                const float2 a2v = *(const float2*)&AsT[kk*68 + m0];
                const float2 b2v = *(const float2*)&BsT[kk*68 + n0];
                acc00 = fmaf(a2v.x, b2v.x, acc00);
                acc01 = fmaf(a2v.x, b2v.y, acc01);
                acc10 = fmaf(a2v.y, b2v.x, acc10);
                acc11 = fmaf(a2v.y, b2v.y, acc11);
            }
            __syncthreads();
        }

        const int c0i = rn + n0, c1i = c0i + 1;
        const float bias0 = (c0i < G4) ? (bihf[c0i] + bhhf[c0i])
                                       : (bihb[c0i-G4] + bhhb[c0i-G4]);
        const float bias1 = (c1i < G4) ? (bihf[c1i] + bhhf[c1i])
                                       : (bihb[c1i-G4] + bhhb[c1i-G4]);
        const long t0 = (long)(bm*64 + m0), t1 = t0 + 1;
        __hip_atomic_store(&gin[t0*N2 + c0i], acc00 + bias0,
                           __ATOMIC_RELAXED, __HIP_MEMORY_SCOPE_AGENT);
        __hip_atomic_store(&gin[t0*N2 + c1i], acc01 + bias1,
                           __ATOMIC_RELAXED, __HIP_MEMORY_SCOPE_AGENT);
        __hip_atomic_store(&gin[t1*N2 + c0i], acc10 + bias0,
                           __ATOMIC_RELAXED, __HIP_MEMORY_SCOPE_AGENT);
        __hip_atomic_store(&gin[t1*N2 + c1i], acc11 + bias1,
                           __ATOMIC_RELAXED, __HIP_MEMORY_SCOPE_AGENT);
        return;
    }

    // ================= LSTM path (r14 structure, verbatim) =================
    const int m8 = blk & 7;
    if (m8 != 0 && m8 != 4) return;     // XCD placement spacers
    const int dir = (m8 == 4);
    const int b   = blk >> 3;           // unit-slice 0..3
    const int u     = tid & 63;
    const int wvid  = tid >> 6;         // 0..15
    const int gate  = wvid >> 2;        // wave-uniform
    const int q     = wvid & 3;         // wave-uniform quarter
    const int unit0 = b*64;
    const int row   = gate*64 + u;            // block-local row 0..255
    const int grow  = gate*HD + unit0 + u;    // gate row 0..1023

    float* hS  = (float*)smem;            // 256 floats
    float* ps  = (float*)(smem + 1024);   // [3][256]
    float* gvS = (float*)(smem + 4096);   // 256 floats

    // --- 64 weights as named SSA float4, loaded ONCE ---
    const float4* W4 = (const float4*)((dir ? Whh_b : Whh_f)
                                       + (long)grow*HD + q*64);
    const float4 wA0  = W4[0],  wA1  = W4[1],  wA2  = W4[2],  wA3  = W4[3];
    const float4 wA4  = W4[4],  wA5  = W4[5],  wA6  = W4[6],  wA7  = W4[7];
    const float4 wA8  = W4[8],  wA9  = W4[9],  wA10 = W4[10], wA11 = W4[11];
    const float4 wA12 = W4[12], wA13 = W4[13], wA14 = W4[14], wA15 = W4[15];

    float cst = 0.f;
    if (tid < 64) cst = c0[dir*HD + unit0 + tid];       // owners: wave 0
    if (tid < HD) hS[tid] = h0[dir*HD + tid];

    float* ginD = gin + dir*G4;
    float gx;
    {   // initial gin word: cold poll
        const long gi0 = (long)(dir ? T_LEN-1 : 0)*N2 + grow;
        do {
            gx = __hip_atomic_load(&ginD[gi0], __ATOMIC_RELAXED,
                                   __HIP_MEMORY_SCOPE_AGENT);
        } while (__float_as_uint(gx) == SENT);
    }

    #pragma unroll 1
    for (int s = 0; s < T_LEN; ++s) {
        const int t = dir ? (T_LEN-1-s) : s;
        float gxn = 0.f;
        long  gidx = 0;
        if (s+1 < T_LEN) {                     // issue next-step gin load EARLY
            gidx = (long)(dir ? t-1 : t+1)*N2 + grow;
            gxn = __hip_atomic_load(&ginD[gidx], __ATOMIC_RELAXED,
                                    __HIP_MEMORY_SCOPE_AGENT);
            __builtin_amdgcn_sched_barrier(0); // pin the early issue
        }

        __syncthreads();                       // (A) hS(s) complete
        const float4* h4 = (const float4*)(hS + q*64);   // uniform-addr broadcast
        float a0=0.f, a1=0.f, a2=0.f, a3=0.f;
        MV(0)  MV(1)  MV(2)  MV(3)
        MV(4)  MV(5)  MV(6)  MV(7)
        MV(8)  MV(9)  MV(10) MV(11)
        MV(12) MV(13) MV(14) MV(15)
        const float a = (a0+a1)+(a2+a3);
        if (q != 0) ps[(q-1)*256 + row] = a;
        __syncthreads();                       // (B) partials ready

        if (q == 0) {                          // waves 0,4,8,12: finalize + activate
            const float raw = a + ps[row] + ps[256+row] + ps[512+row] + gx;
            gvS[row] = (gate == 2) ? tanhf(raw) : 1.f/(1.f + expf(-raw));
        }
        __syncthreads();                       // (C) gvS ready

        if (tid < 64) {                        // wave 0 = owners: c/h update + publish
            const float i_ = gvS[tid],       f_ = gvS[64+tid];
            const float g_ = gvS[128+tid],   o_ = gvS[192+tid];
            cst = fmaf(f_, cst, i_*g_);
            const float hv = o_ * tanhf(cst);
            hS[unit0 + tid] = hv;              // own slice: LDS only
            __hip_atomic_store(&Hh[(long)t*512 + dir*HD + unit0 + tid], hv,
                               __ATOMIC_RELAXED, __HIP_MEMORY_SCOPE_AGENT);
        } else if (tid < 256 && s+1 < T_LEN) { // waves 1-3: poll one foreign word each
            const int fidx = tid - 64;                      // 0..191
            const int gu   = (fidx < unit0) ? fidx : fidx + 64;
            const long idx = (long)t*512 + dir*HD + gu;
            float v;
            do {
                v = __hip_atomic_load(&Hh[idx], __ATOMIC_RELAXED,
                                      __HIP_MEMORY_SCOPE_AGENT);
            } while (__float_as_uint(v) == SENT);
            hS[gu] = v;
        }

        if (s+1 < T_LEN) {                     // check-late: usually already ready
            while (__float_as_uint(gxn) == SENT)
                gxn = __hip_atomic_load(&ginD[gidx], __ATOMIC_RELAXED,
                                        __HIP_MEMORY_SCOPE_AGENT);
        }
        gx = gxn;
    }
}

// ---------------------------------------------------------------------------
// Kernel 3: feats[t][tag] = [hf|hb][t] . W_tag[tag] + b_tag  (separate kernel
// — r18 proved polling-consumer fusion slows the LSTM's coherence path)
// ---------------------------------------------------------------------------
__global__ __launch_bounds__(192) void feats_kernel(
    const float* __restrict__ Hhist, const float* __restrict__ Wtag,
    const float* __restrict__ btag, float* __restrict__ feats)
{
    __shared__ __align__(16) float Ws[TAGS][512];
    const int tid = threadIdx.x;
    for (int i = tid; i < TAGS*512; i += 192) Ws[0][i] = Wtag[i];
    __syncthreads();
    const int tl = tid / TAGS;            // 0..15
    const int tg = tid % TAGS;
    const int t  = blockIdx.x * 16 + tl;
    const float4* hrow = (const float4*)(Hhist + (long)t*512);
    const float4* wrow = (const float4*)(&Ws[tg][0]);
    float a0=0.f,a1=0.f,a2=0.f,a3=0.f;
    #pragma unroll 8
    for (int k = 0; k < 128; ++k) {
        const float4 h = hrow[k];
        const float4 ww = wrow[k];
        a0=fmaf(h.x,ww.x,a0); a1=fmaf(h.y,ww.y,a1);
        a2=fmaf(h.z,ww.z,a2); a3=fmaf(h.w,ww.w,a3);
    }
    feats[t*TAGS + tg] = ((a0+a1)+(a2+a3)) + btag[tg];
}

// ---------------------------------------------------------------------------
// Kernel 4: Viterbi — 3-phase, single wave.
// Phase 1 (new): fv kept as wave-uniform registers broadcast via v_readlane
// (no LDS round trip, no barriers in the inner loop). Lane `to` computes
// new fv[to] (12 adds + balanced fmax tree + feat add — candidate values
// bit-identical to the reference; max is order-invariant; readlane moves
// bits exactly). Feat for step s+1 prefetched to hide the ds_read.
// Phases 2/3: r17 structure (register-batched bp recovery, serial backtrack).
// ---------------------------------------------------------------------------
__device__ __forceinline__ float rlane(float v, int l) {
    return __uint_as_float((unsigned)__builtin_amdgcn_readlane(
        (int)__float_as_uint(v), l));
}

__global__ __launch_bounds__(64) void viterbi_kernel(
    const float* __restrict__ feats, const float* __restrict__ trans,
    float* __restrict__ fvstore, float* __restrict__ out)
{
    __shared__ __align__(16) float fS[VCH*TAGS];        // 24 KB feats chunk
    __shared__ __align__(16) float trS[TAGS*TAGS];
    __shared__ unsigned char bps[T_LEN*TAGS];           // 48 KB backpointers
    const int lane = threadIdx.x;

    for (int i = lane; i < TAGS*TAGS; i += 64) trS[i] = trans[i];

    const int trow = (lane < TAGS) ? lane : 0;
    float tr[TAGS];
    #pragma unroll
    for (int f = 0; f < TAGS; ++f) tr[f] = trans[trow*TAGS + f];

    // fv as wave-uniform values (readlane-broadcast each step);
    // nf = this lane's own fv[lane] (lane < TAGS).
    float fv[TAGS];
    #pragma unroll
    for (int f = 0; f < TAGS; ++f) fv[f] = (f == 10) ? 0.f : NEGV;  // START=10
    float nf = (lane == 10) ? 0.f : NEGV;

    // ---------------- Phase 1: forward max-scan (no-barrier inner loop) ----
    for (int c = 0; c < T_LEN/VCH; ++c) {
        __syncthreads();
        {
            const float4* src = (const float4*)(feats + (long)c*VCH*TAGS);
            float4* dst = (float4*)fS;
            #pragma unroll 4
            for (int i = lane; i < VCH*TAGS/4; i += 64) dst[i] = src[i];
        }
        __syncthreads();
        float fcur = fS[trow];                       // feat for s=0 of chunk
        #pragma unroll 1
        for (int s = 0; s < VCH; ++s) {
            const int t = c*VCH + s;
            const float fnext = (s+1 < VCH) ? fS[(s+1)*TAGS + trow] : 0.f;
            if (lane < TAGS)
                fvstore[(long)t*TAGS + lane] = nf;   // fv_pre (fire&forget)
            float cand[TAGS];
            #pragma unroll
            for (int f = 0; f < TAGS; ++f) cand[f] = fv[f] + tr[f];
            const float m =
                fmaxf(fmaxf(fmaxf(fmaxf(cand[0],cand[1]), fmaxf(cand[2],cand[3])),
                            fmaxf(fmaxf(cand[4],cand[5]), fmaxf(cand[6],cand[7]))),
                      fmaxf(fmaxf(cand[8],cand[9]), fmaxf(cand[10],cand[11])));
            nf = m + fcur;                           // lane `to`'s new fv[to]
            #pragma unroll
            for (int f = 0; f < TAGS; ++f) fv[f] = rlane(nf, f);
            fcur = fnext;
        }
    }

    // ---------------- Phase 2: parallel backpointer recovery ----------------
    __syncthreads();
    for (int t = lane; t < T_LEN; t += 64) {
        const float4 F0 = *(const float4*)(fvstore + (long)t*TAGS);
        const float4 F1 = *(const float4*)(fvstore + (long)t*TAGS + 4);
        const float4 F2 = *(const float4*)(fvstore + (long)t*TAGS + 8);
        const float fp[TAGS] = {F0.x,F0.y,F0.z,F0.w,
                                F1.x,F1.y,F1.z,F1.w,
                                F2.x,F2.y,F2.z,F2.w};
        #pragma unroll
        for (int to = 0; to < TAGS; ++to) {
            float best = -3.4e38f; int bp = 0;
            #pragma unroll
            for (int f = 0; f < TAGS; ++f) {
                const float v = fp[f] + trS[to*TAGS + f];
                if (v > best) { best = v; bp = f; }   // strict > = np first-max
            }
            bps[t*TAGS + to] = (unsigned char)bp;
        }
    }
    __syncthreads();

    // ---------------- Phase 3: terminal + serial backtrack ----------------
    if (lane == 0) {
        float bestv = -3.4e38f; int best = 0;
        #pragma unroll
        for (int g = 0; g < TAGS; ++g) {
            const float v = fv[g] + trS[11*TAGS + g];     // STOP = 11
            if (v > bestv) { bestv = v; best = g; }
        }
        out[0] = bestv;
        int cur = best;
        for (int t = T_LEN-1; t >= 0; --t) {
            out[1+t] = (float)cur;
            cur = bps[t*TAGS + cur];
        }
    }
}

// ---------------------------------------------------------------------------
// Host launch.  ws layout (floats):
//   gin     [4096*2048] = 33.5 MB  (0x7F sentinel-filled each launch)
//   Hh      [4096*512]  =  8.4 MB  (0x7F sentinel-filled each launch)
//   feats   [4096*12]   =  0.2 MB
//   fvstore [4096*12]   =  0.2 MB
// ---------------------------------------------------------------------------
extern "C" void kernel_launch(void* const* d_in, const int* in_sizes, int n_in,
                              void* d_out, int out_size, void* d_ws, size_t ws_size,
                              hipStream_t stream)
{
    (void)in_sizes; (void)n_in; (void)out_size; (void)ws_size;
    const int*   sentence = (const int*)  d_in[0];
    const float* h0       = (const float*)d_in[1];
    const float* c0       = (const float*)d_in[2];
    const float* embed    = (const float*)d_in[3];
    const float* Wihf     = (const float*)d_in[4];
    const float* Whhf     = (const float*)d_in[5];
    const float* bihf     = (const float*)d_in[6];
    const float* bhhf     = (const float*)d_in[7];
    const float* Wihb     = (const float*)d_in[8];
    const float* Whhb     = (const float*)d_in[9];
    const float* bihb     = (const float*)d_in[10];
    const float* bhhb     = (const float*)d_in[11];
    const float* Wtag     = (const float*)d_in[12];
    const float* btag     = (const float*)d_in[13];
    const float* trans    = (const float*)d_in[14];
    float* out = (float*)d_out;

    float* gin     = (float*)d_ws;
    float* Hh      = gin   + (long)T_LEN*N2;
    float* feats   = Hh    + (long)T_LEN*512;
    float* fvstore = feats + (long)T_LEN*TAGS;

    hipMemsetAsync(gin, 0x7F, (size_t)T_LEN*N2*sizeof(float), stream);
    hipMemsetAsync(Hh,  0x7F, (size_t)T_LEN*512*sizeof(float), stream);

    fused_gemm_lstm<<<NLSTM + 2048, 1024, 0, stream>>>(
        sentence, embed, Wihf, Wihb, bihf, bhhf, bihb, bhhb,
        Whhf, Whhb, h0, c0, gin, Hh);
    feats_kernel<<<T_LEN/16, 192, 0, stream>>>(Hh, Wtag, btag, feats);
    viterbi_kernel<<<1, 64, 0, stream>>>(feats, trans, fvstore, out);
}